// Round 14
// baseline (417.989 us; speedup 1.0000x reference)
//
#include <hip/hip_runtime.h>
#include <hip/hip_bf16.h>

// TurboQuantMSE: x_hat = Q(x @ R^T) @ R, Q = 16-level Lloyd-Max quantizer.
// Round 14: R12's producer-consumer + consumer software pipeline, with the
// spill fixed: __launch_bounds__(768,2) (R12's (768,3) capped VGPR ~170 and
// spilled the P/Q/R fragment sets -> WRITE_SIZE 427MB, 13% MfmaUtil; one
// 12-wave block gives 3 waves/SIMD regardless, so bound=2 just frees the
// register allocator; need ~200 VGPR < 256 cap). Consumer per tile:
// {issue kk1(t) reads | lgkm(8) | MFMA kk0 | issue kk0(t+1) reads | lgkm(8) |
// MFMA kk1 | barrier} — reads stay in flight under every MFMA cluster.
// Producers: stage(t+2), vmcnt(0), barrier. 3 LDS buffers (144KB).

typedef __attribute__((ext_vector_type(8))) _Float16 f16x8;
typedef __attribute__((ext_vector_type(4))) float f32x4;

__device__ __forceinline__ unsigned short f2h(float f) {
    _Float16 h = (_Float16)f;
    return *reinterpret_cast<unsigned short*>(&h);
}

__device__ __forceinline__ float quant16(float yn, const float* c) {
    float v = c[0];
#pragma unroll
    for (int i = 0; i < 15; i++) {
        const float bnd = 0.5f * (c[i] + c[i + 1]);
        v = (yn > bnd) ? c[i + 1] : v;
    }
    return v;
}

// ---------------- elementwise f32 -> fp16 (x) ----------------
__global__ __launch_bounds__(256) void convert_x_kernel(
    const float* __restrict__ x, unsigned short* __restrict__ xb) {
    const int i = (blockIdx.x * 256 + threadIdx.x) * 4;
    float4 v = *reinterpret_cast<const float4*>(x + i);
    ushort4 b;
    b.x = f2h(v.x); b.y = f2h(v.y); b.z = f2h(v.z); b.w = f2h(v.w);
    *reinterpret_cast<ushort4*>(xb + i) = b;
}

// ---------------- rotation f32 -> fp16 (row-major) + fp16 transposed --------
__global__ __launch_bounds__(256) void conv_rot_kernel(
    const float* __restrict__ R, unsigned short* __restrict__ Rb,
    unsigned short* __restrict__ Rt) {
    __shared__ float t[64][65];
    const int tid = threadIdx.x;
    const int tr = blockIdx.y * 64, tc = blockIdx.x * 64;
    const int r0 = tid >> 4;
    const int c4 = (tid & 15) << 2;
#pragma unroll
    for (int i = 0; i < 4; i++) {
        const int r = r0 + i * 16;
        float4 v = *reinterpret_cast<const float4*>(
            &R[(size_t)(tr + r) * 4096 + tc + c4]);
        ushort4 b;
        b.x = f2h(v.x); b.y = f2h(v.y); b.z = f2h(v.z); b.w = f2h(v.w);
        *reinterpret_cast<ushort4*>(&Rb[(size_t)(tr + r) * 4096 + tc + c4]) = b;
        t[r][c4 + 0] = v.x; t[r][c4 + 1] = v.y;
        t[r][c4 + 2] = v.z; t[r][c4 + 3] = v.w;
    }
    __syncthreads();
#pragma unroll
    for (int i = 0; i < 16; i++) {
        const int idx = tid + 256 * i;
        const int rr = idx >> 6;
        const int cc = idx & 63;
        Rt[(size_t)(tc + rr) * 4096 + tr + cc] = f2h(t[cc][rr]);
    }
}

// ---------------- producer/consumer pipelined NT GEMM ------------------------
// C[2048,4096] = A[2048,K] * Bt[4096,K]^T, fp16 in, f32 accum.
// BM=128 BN=256 BK=64. Waves 0..7 consume (64x64, acc[4][4]); 8..11 produce.
// 3 LDS buffers x 48KB. One barrier/tile.
constexpr int GK = 4096;
constexpr int BM = 128, BN = 256, BK = 64;
constexpr int NT = GK / BK;                 // 64
constexpr int A_LDS = BM * BK * 2;          // 16384
constexpr int BUF = (BM + BN) * BK * 2;     // 49152
constexpr int LDS_DYN = 3 * BUF;            // 147456

template <bool QUANT>
__global__ __launch_bounds__(768, 2) void gemm_nt_kernel(
    const unsigned short* __restrict__ A, const unsigned short* __restrict__ Bt,
    void* __restrict__ Cout, const float* __restrict__ cb16) {
    extern __shared__ char smem[];
    const int tid = threadIdx.x;
    const int lane = tid & 63;
    const int w = tid >> 6;        // 0..11

    // XCD-aware bijective swizzle (256 blocks, 256%8==0)
    const int bid = blockIdx.x;
    const int wgid = (bid & 7) * 32 + (bid >> 3);
    const int tn = wgid & 15;      // N/BN = 16
    const int tm = wgid >> 4;      // M/BM = 16

    if (w >= 8) {
        // ================= PRODUCER (waves 8..11) =================
        const int tp = tid - 512;            // 0..255
        const int pw = tp >> 6;              // 0..3
        const int prow = tp >> 3;            // 0..31
        const int pcol = (((tp & 7) ^ (prow & 7)) << 3);  // pre-swizzled col
        const unsigned short* P[12];
#pragma unroll
        for (int r = 0; r < 12; r++) {
            const int rir = r * 32 + prow;   // row in 48KB region
            P[r] = (rir < BM)
                ? A + (size_t)(tm * BM + rir) * GK + pcol
                : Bt + (size_t)(tn * BN + (rir - BM)) * GK + pcol;
        }
#define PSTAGE(dstbase)                                                        \
        {                                                                      \
            _Pragma("unroll")                                                  \
            for (int r = 0; r < 12; r++) {                                     \
                __builtin_amdgcn_global_load_lds(                              \
                    (const __attribute__((address_space(1))) void*)P[r],       \
                    (__attribute__((address_space(3))) void*)(                 \
                        smem + (dstbase) + r * 4096 + pw * 1024), 16, 0, 0);   \
                P[r] += BK;                                                    \
            }                                                                  \
        }
        // prologue: stage tiles 0,1
        PSTAGE(0)
        PSTAGE(BUF)
        asm volatile("s_waitcnt vmcnt(0)" ::: "memory");
        __builtin_amdgcn_s_barrier();
        __builtin_amdgcn_sched_barrier(0);
        int wb = 2 * BUF;
        for (int t = 0; t < NT; ++t) {
            if (t + 2 < NT) PSTAGE(wb)
            asm volatile("s_waitcnt vmcnt(0)" ::: "memory");
            __builtin_amdgcn_s_barrier();
            __builtin_amdgcn_sched_barrier(0);
            wb = (wb == 2 * BUF) ? 0 : wb + BUF;
        }
#undef PSTAGE
        return;
    }

    // ================= CONSUMER (waves 0..7) =================
    const int wm = w >> 2;         // 0..1
    const int wn = w & 3;          // 0..3

    f32x4 acc[4][4];
#pragma unroll
    for (int m = 0; m < 4; m++)
#pragma unroll
        for (int n = 0; n < 4; n++) acc[m][n] = (f32x4){0.f, 0.f, 0.f, 0.f};

    // fragment read addressing (swizzled): byte = row*128 + (kslot^row&7)*16
    const int frow = lane & 15;
    const int sw0 = (((lane >> 4) ^ (frow & 7)) << 4);        // kk=0
    const int sw1 = (((4 + (lane >> 4)) ^ (frow & 7)) << 4);  // kk=1
    const int arow = (wm * 64 + frow) * 128;
    const int brow = A_LDS + (wn * 64 + frow) * 128;

#define LDA(base, m, sw) (*reinterpret_cast<const f16x8*>(smem + (base) + arow + (m) * 2048 + (sw)))
#define LDB(base, n, sw) (*reinterpret_cast<const f16x8*>(smem + (base) + brow + (n) * 2048 + (sw)))
#define MFMA16(A0, A1, A2, A3, B0, B1, B2, B3)                                     \
    acc[0][0] = __builtin_amdgcn_mfma_f32_16x16x32_f16(A0, B0, acc[0][0], 0, 0, 0); \
    acc[0][1] = __builtin_amdgcn_mfma_f32_16x16x32_f16(A0, B1, acc[0][1], 0, 0, 0); \
    acc[0][2] = __builtin_amdgcn_mfma_f32_16x16x32_f16(A0, B2, acc[0][2], 0, 0, 0); \
    acc[0][3] = __builtin_amdgcn_mfma_f32_16x16x32_f16(A0, B3, acc[0][3], 0, 0, 0); \
    acc[1][0] = __builtin_amdgcn_mfma_f32_16x16x32_f16(A1, B0, acc[1][0], 0, 0, 0); \
    acc[1][1] = __builtin_amdgcn_mfma_f32_16x16x32_f16(A1, B1, acc[1][1], 0, 0, 0); \
    acc[1][2] = __builtin_amdgcn_mfma_f32_16x16x32_f16(A1, B2, acc[1][2], 0, 0, 0); \
    acc[1][3] = __builtin_amdgcn_mfma_f32_16x16x32_f16(A1, B3, acc[1][3], 0, 0, 0); \
    acc[2][0] = __builtin_amdgcn_mfma_f32_16x16x32_f16(A2, B0, acc[2][0], 0, 0, 0); \
    acc[2][1] = __builtin_amdgcn_mfma_f32_16x16x32_f16(A2, B1, acc[2][1], 0, 0, 0); \
    acc[2][2] = __builtin_amdgcn_mfma_f32_16x16x32_f16(A2, B2, acc[2][2], 0, 0, 0); \
    acc[2][3] = __builtin_amdgcn_mfma_f32_16x16x32_f16(A2, B3, acc[2][3], 0, 0, 0); \
    acc[3][0] = __builtin_amdgcn_mfma_f32_16x16x32_f16(A3, B0, acc[3][0], 0, 0, 0); \
    acc[3][1] = __builtin_amdgcn_mfma_f32_16x16x32_f16(A3, B1, acc[3][1], 0, 0, 0); \
    acc[3][2] = __builtin_amdgcn_mfma_f32_16x16x32_f16(A3, B2, acc[3][2], 0, 0, 0); \
    acc[3][3] = __builtin_amdgcn_mfma_f32_16x16x32_f16(A3, B3, acc[3][3], 0, 0, 0);

    // frag sets: P/Q = kk0 of cur/next tile (alternate), R = kk1 of cur tile
    f16x8 Pa0, Pa1, Pa2, Pa3, Pb0, Pb1, Pb2, Pb3;
    f16x8 Qa0, Qa1, Qa2, Qa3, Qb0, Qb1, Qb2, Qb3;
    f16x8 Ra0, Ra1, Ra2, Ra3, Rb0, Rb1, Rb2, Rb3;

#define LOADSET(S, base, sw)                                                   \
    S##a0 = LDA(base, 0, sw); S##a1 = LDA(base, 1, sw);                        \
    S##a2 = LDA(base, 2, sw); S##a3 = LDA(base, 3, sw);                        \
    S##b0 = LDB(base, 0, sw); S##b1 = LDB(base, 1, sw);                        \
    S##b2 = LDB(base, 2, sw); S##b3 = LDB(base, 3, sw);

    // prologue: wait producers' tiles 0,1; preload kk0(0) into P
    __builtin_amdgcn_s_barrier();
    __builtin_amdgcn_sched_barrier(0);
    int lb0 = 0, lb1 = BUF;   // buf of tile t, tile t+1
    LOADSET(P, 0, sw0)

#define CBODY(CUR, NXT, t)                                                     \
    {                                                                          \
        LOADSET(R, lb0, sw1)                   /* kk1(t): 8 reads */           \
        asm volatile("s_waitcnt lgkmcnt(8)" ::: "memory");  /* kk0(t) done */  \
        __builtin_amdgcn_sched_barrier(0);                                     \
        __builtin_amdgcn_s_setprio(1);                                         \
        MFMA16(CUR##a0, CUR##a1, CUR##a2, CUR##a3,                             \
               CUR##b0, CUR##b1, CUR##b2, CUR##b3)                             \
        __builtin_amdgcn_s_setprio(0);                                         \
        if ((t) + 1 < NT) {                                                    \
            LOADSET(NXT, lb1, sw0)             /* kk0(t+1): 8 reads */         \
            asm volatile("s_waitcnt lgkmcnt(8)" ::: "memory"); /* kk1(t) */    \
        } else {                                                               \
            asm volatile("s_waitcnt lgkmcnt(0)" ::: "memory");                 \
        }                                                                      \
        __builtin_amdgcn_sched_barrier(0);                                     \
        __builtin_amdgcn_s_setprio(1);                                         \
        MFMA16(Ra0, Ra1, Ra2, Ra3, Rb0, Rb1, Rb2, Rb3)                         \
        __builtin_amdgcn_s_setprio(0);                                         \
        __builtin_amdgcn_s_barrier();                                          \
        __builtin_amdgcn_sched_barrier(0);                                     \
        lb0 = lb1;                                                             \
        lb1 = (lb1 == 2 * BUF) ? 0 : lb1 + BUF;                                \
    }

    for (int t = 0; t < NT; t += 2) {
        CBODY(P, Q, t)
        CBODY(Q, P, t + 1)
    }
#undef CBODY
#undef LOADSET
#undef LDA
#undef LDB
#undef MFMA16

    // ---- epilogue: C/D layout col=lane&15, row=(lane>>4)*4+j ----
    const int crow0 = tm * BM + wm * 64 + ((lane >> 4) << 2);
    const int ccol0 = tn * BN + wn * 64 + frow;
    if constexpr (QUANT) {
        float c[16];
#pragma unroll
        for (int i = 0; i < 16; i++) c[i] = cb16[i];
        unsigned short* O = (unsigned short*)Cout;
#pragma unroll
        for (int m = 0; m < 4; m++)
#pragma unroll
            for (int n = 0; n < 4; n++)
#pragma unroll
                for (int j = 0; j < 4; j++)
                    O[(size_t)(crow0 + m * 16 + j) * 4096 + ccol0 + n * 16] =
                        f2h(quant16(acc[m][n][j] * 64.0f, c) * 0.015625f);
    } else {
        float* O = (float*)Cout;
#pragma unroll
        for (int m = 0; m < 4; m++)
#pragma unroll
            for (int n = 0; n < 4; n++)
#pragma unroll
                for (int j = 0; j < 4; j++)
                    O[(size_t)(crow0 + m * 16 + j) * 4096 + ccol0 + n * 16] =
                        acc[m][n][j];
    }
}

extern "C" void kernel_launch(void* const* d_in, const int* in_sizes, int n_in,
                              void* d_out, int out_size, void* d_ws,
                              size_t ws_size, hipStream_t stream) {
    const float* x = (const float*)d_in[0];
    const float* rot = (const float*)d_in[1];
    const float* cb = (const float*)d_in[2];
    float* out = (float*)d_out;

    unsigned short* Xh = (unsigned short*)d_ws;
    unsigned short* Rh = Xh + (size_t)2048 * 4096;
    unsigned short* Rt = Rh + (size_t)4096 * 4096;
    unsigned short* Yh = Rt + (size_t)4096 * 4096;

    (void)hipFuncSetAttribute(
        reinterpret_cast<const void*>(&gemm_nt_kernel<true>),
        hipFuncAttributeMaxDynamicSharedMemorySize, LDS_DYN);
    (void)hipFuncSetAttribute(
        reinterpret_cast<const void*>(&gemm_nt_kernel<false>),
        hipFuncAttributeMaxDynamicSharedMemorySize, LDS_DYN);

    convert_x_kernel<<<8192, 256, 0, stream>>>(x, Xh);
    conv_rot_kernel<<<dim3(64, 64), 256, 0, stream>>>(rot, Rh, Rt);
    // y = x @ R^T : NT GEMM, Bt = Rh
    gemm_nt_kernel<true><<<256, 768, LDS_DYN, stream>>>(Xh, Rh, (void*)Yh, cb);
    // x_hat = y_hat @ R = y_hat @ (R^T)^T : NT GEMM, Bt = Rt
    gemm_nt_kernel<false><<<256, 768, LDS_DYN, stream>>>(Yh, Rt, (void*)out, nullptr);
}

// Round 16
// 176.658 us; speedup vs baseline: 2.3661x; 2.3661x over previous
//
#include <hip/hip_runtime.h>
#include <hip/hip_bf16.h>

// TurboQuantMSE: x_hat = Q(x @ R^T) @ R, Q = 16-level Lloyd-Max quantizer.
// Round 16: R15's producer-consumer + 2-set cross-tile fragment pipeline with
// the LEDGER FIX: producer waits vmcnt(6) (not 12) so tile t+2 is landed at
// barrier B_t — body t+1's prefetch reads tile t+2 right after B_t, so it
// must land one barrier earlier than R15 assumed (R15's race: consumer read
// one-barrier-stale LDS -> absmax 0.2). Consumers: issue reads(t+1) into the
// spare frag set, lgkm(8) (waits only tile t's reads), 16 MFMA, barrier —
// lgkm never drains. Producers: stage t+3 into buf[(t+3)&3], vmcnt(6),
// barrier — vmcnt never drains. 4 LDS buffers x 24KB, BK=32.

typedef __attribute__((ext_vector_type(8))) _Float16 f16x8;
typedef __attribute__((ext_vector_type(4))) float f32x4;

__device__ __forceinline__ unsigned short f2h(float f) {
    _Float16 h = (_Float16)f;
    return *reinterpret_cast<unsigned short*>(&h);
}

__device__ __forceinline__ float quant16(float yn, const float* c) {
    float v = c[0];
#pragma unroll
    for (int i = 0; i < 15; i++) {
        const float bnd = 0.5f * (c[i] + c[i + 1]);
        v = (yn > bnd) ? c[i + 1] : v;
    }
    return v;
}

// ---------------- elementwise f32 -> fp16 (x) ----------------
__global__ __launch_bounds__(256) void convert_x_kernel(
    const float* __restrict__ x, unsigned short* __restrict__ xb) {
    const int i = (blockIdx.x * 256 + threadIdx.x) * 4;
    float4 v = *reinterpret_cast<const float4*>(x + i);
    ushort4 b;
    b.x = f2h(v.x); b.y = f2h(v.y); b.z = f2h(v.z); b.w = f2h(v.w);
    *reinterpret_cast<ushort4*>(xb + i) = b;
}

// ---------------- rotation f32 -> fp16 (row-major) + fp16 transposed --------
__global__ __launch_bounds__(256) void conv_rot_kernel(
    const float* __restrict__ R, unsigned short* __restrict__ Rb,
    unsigned short* __restrict__ Rt) {
    __shared__ float t[64][65];
    const int tid = threadIdx.x;
    const int tr = blockIdx.y * 64, tc = blockIdx.x * 64;
    const int r0 = tid >> 4;
    const int c4 = (tid & 15) << 2;
#pragma unroll
    for (int i = 0; i < 4; i++) {
        const int r = r0 + i * 16;
        float4 v = *reinterpret_cast<const float4*>(
            &R[(size_t)(tr + r) * 4096 + tc + c4]);
        ushort4 b;
        b.x = f2h(v.x); b.y = f2h(v.y); b.z = f2h(v.z); b.w = f2h(v.w);
        *reinterpret_cast<ushort4*>(&Rb[(size_t)(tr + r) * 4096 + tc + c4]) = b;
        t[r][c4 + 0] = v.x; t[r][c4 + 1] = v.y;
        t[r][c4 + 2] = v.z; t[r][c4 + 3] = v.w;
    }
    __syncthreads();
#pragma unroll
    for (int i = 0; i < 16; i++) {
        const int idx = tid + 256 * i;
        const int rr = idx >> 6;
        const int cc = idx & 63;
        Rt[(size_t)(tc + rr) * 4096 + tr + cc] = f2h(t[cc][rr]);
    }
}

// ---------------- producer/consumer pipelined NT GEMM ------------------------
// C[2048,4096] = A[2048,K] * Bt[4096,K]^T, fp16 in, f32 accum.
// BM=128 BN=256 BK=32. Waves 0..7 consume (64x64, acc[4][4]); 8..11 produce.
// 4 LDS buffers x 24KB (A 8KB + B 16KB each). LDS rows = 64B.
constexpr int GK = 4096;
constexpr int BM = 128, BN = 256, BK = 32;
constexpr int NT = GK / BK;                 // 128
constexpr int A_LDS = BM * BK * 2;          // 8192
constexpr int BUF = (BM + BN) * BK * 2;     // 24576
constexpr int LDS_DYN = 4 * BUF;            // 98304

template <bool QUANT>
__global__ __launch_bounds__(768, 3) void gemm_nt_kernel(
    const unsigned short* __restrict__ A, const unsigned short* __restrict__ Bt,
    void* __restrict__ Cout, const float* __restrict__ cb16) {
    extern __shared__ char smem[];
    const int tid = threadIdx.x;
    const int lane = tid & 63;
    const int w = tid >> 6;        // 0..11

    // XCD-aware bijective swizzle (256 blocks, 256%8==0)
    const int bid = blockIdx.x;
    const int wgid = (bid & 7) * 32 + (bid >> 3);
    const int tn = wgid & 15;      // N/BN = 16
    const int tm = wgid >> 4;      // M/BM = 16

    if (w >= 8) {
        // ================= PRODUCER (waves 8..11) =================
        const int tp = tid - 512;            // 0..255
        const int prow = tp >> 2;            // 0..63
        const int scol = (((tp & 3) ^ ((prow >> 1) & 3)) << 3);  // pre-swz col
        const int tb = tp << 4;              // byte offset within 4KB chunk
        const unsigned short* pA0 = A + (size_t)(tm * BM + prow) * GK + scol;
        const unsigned short* pA1 = pA0 + (size_t)64 * GK;
        const unsigned short* pB0 = Bt + (size_t)(tn * BN + prow) * GK + scol;
        const unsigned short* pB1 = pB0 + (size_t)64 * GK;
        const unsigned short* pB2 = pB0 + (size_t)128 * GK;
        const unsigned short* pB3 = pB0 + (size_t)192 * GK;
#define GLL(src, off)                                                          \
        __builtin_amdgcn_global_load_lds(                                      \
            (const __attribute__((address_space(1))) void*)(src),              \
            (__attribute__((address_space(3))) void*)(smem + (off) + tb),      \
            16, 0, 0);
#define PSTAGE(dstbase)                                                        \
        {                                                                      \
            GLL(pA0, (dstbase) + 0)                                            \
            GLL(pA1, (dstbase) + 4096)                                         \
            GLL(pB0, (dstbase) + 8192)                                         \
            GLL(pB1, (dstbase) + 12288)                                        \
            GLL(pB2, (dstbase) + 16384)                                        \
            GLL(pB3, (dstbase) + 20480)                                        \
            pA0 += BK; pA1 += BK; pB0 += BK; pB1 += BK; pB2 += BK; pB3 += BK;  \
        }
        // prologue: stage tiles 0,1,2; tiles 0,1 must be landed (18 -> 6)
        PSTAGE(0)
        PSTAGE(BUF)
        PSTAGE(2 * BUF)
        asm volatile("s_waitcnt vmcnt(6)" ::: "memory");
        __builtin_amdgcn_s_barrier();
        __builtin_amdgcn_sched_barrier(0);
        for (int t = 0; t < NT; ++t) {
            if (t + 3 < NT) PSTAGE(((t + 3) & 3) * BUF)
            // tile t+2 must be landed at barrier B_t (consumer prefetches
            // t+2 right after B_t):
            if (t + 3 < NT) {
                // outstanding = {t+2:6, t+3:6} -> retire t+2
                asm volatile("s_waitcnt vmcnt(6)" ::: "memory");
            } else {
                // outstanding <= {t+2:6} -> retire all
                asm volatile("s_waitcnt vmcnt(0)" ::: "memory");
            }
            __builtin_amdgcn_s_barrier();
            __builtin_amdgcn_sched_barrier(0);
        }
#undef PSTAGE
#undef GLL
        return;
    }

    // ================= CONSUMER (waves 0..7) =================
    const int wm = w >> 2;         // 0..1
    const int wn = w & 3;          // 0..3

    f32x4 acc[4][4];
#pragma unroll
    for (int m = 0; m < 4; m++)
#pragma unroll
        for (int n = 0; n < 4; n++) acc[m][n] = (f32x4){0.f, 0.f, 0.f, 0.f};

    // fragment read addressing (swizzled): byte = row*64 + (kslot^((row>>1)&3))*16
    const int frow = lane & 15;
    const int sw = (((lane >> 4) ^ ((frow >> 1) & 3)) << 4);
    const int arow = (wm * 64 + frow) * 64;
    const int brow = A_LDS + (wn * 64 + frow) * 64;

#define LDA(base, m) (*reinterpret_cast<const f16x8*>(smem + (base) + arow + (m) * 1024 + sw))
#define LDB(base, n) (*reinterpret_cast<const f16x8*>(smem + (base) + brow + (n) * 1024 + sw))
#define MFMA16(A0, A1, A2, A3, B0, B1, B2, B3)                                     \
    acc[0][0] = __builtin_amdgcn_mfma_f32_16x16x32_f16(A0, B0, acc[0][0], 0, 0, 0); \
    acc[0][1] = __builtin_amdgcn_mfma_f32_16x16x32_f16(A0, B1, acc[0][1], 0, 0, 0); \
    acc[0][2] = __builtin_amdgcn_mfma_f32_16x16x32_f16(A0, B2, acc[0][2], 0, 0, 0); \
    acc[0][3] = __builtin_amdgcn_mfma_f32_16x16x32_f16(A0, B3, acc[0][3], 0, 0, 0); \
    acc[1][0] = __builtin_amdgcn_mfma_f32_16x16x32_f16(A1, B0, acc[1][0], 0, 0, 0); \
    acc[1][1] = __builtin_amdgcn_mfma_f32_16x16x32_f16(A1, B1, acc[1][1], 0, 0, 0); \
    acc[1][2] = __builtin_amdgcn_mfma_f32_16x16x32_f16(A1, B2, acc[1][2], 0, 0, 0); \
    acc[1][3] = __builtin_amdgcn_mfma_f32_16x16x32_f16(A1, B3, acc[1][3], 0, 0, 0); \
    acc[2][0] = __builtin_amdgcn_mfma_f32_16x16x32_f16(A2, B0, acc[2][0], 0, 0, 0); \
    acc[2][1] = __builtin_amdgcn_mfma_f32_16x16x32_f16(A2, B1, acc[2][1], 0, 0, 0); \
    acc[2][2] = __builtin_amdgcn_mfma_f32_16x16x32_f16(A2, B2, acc[2][2], 0, 0, 0); \
    acc[2][3] = __builtin_amdgcn_mfma_f32_16x16x32_f16(A2, B3, acc[2][3], 0, 0, 0); \
    acc[3][0] = __builtin_amdgcn_mfma_f32_16x16x32_f16(A3, B0, acc[3][0], 0, 0, 0); \
    acc[3][1] = __builtin_amdgcn_mfma_f32_16x16x32_f16(A3, B1, acc[3][1], 0, 0, 0); \
    acc[3][2] = __builtin_amdgcn_mfma_f32_16x16x32_f16(A3, B2, acc[3][2], 0, 0, 0); \
    acc[3][3] = __builtin_amdgcn_mfma_f32_16x16x32_f16(A3, B3, acc[3][3], 0, 0, 0);

    f16x8 Pa0, Pa1, Pa2, Pa3, Pb0, Pb1, Pb2, Pb3;
    f16x8 Qa0, Qa1, Qa2, Qa3, Qb0, Qb1, Qb2, Qb3;

#define LOADSET(S, base)                                                       \
    S##a0 = LDA(base, 0); S##a1 = LDA(base, 1);                                \
    S##a2 = LDA(base, 2); S##a3 = LDA(base, 3);                                \
    S##b0 = LDB(base, 0); S##b1 = LDB(base, 1);                                \
    S##b2 = LDB(base, 2); S##b3 = LDB(base, 3);

    // prologue: wait producers' tiles 0,1; issue reads(0) into P
    __builtin_amdgcn_s_barrier();
    __builtin_amdgcn_sched_barrier(0);
    LOADSET(P, 0)

#define CBODY(CUR, NXT, t)                                                     \
    {                                                                          \
        if ((t) + 1 < NT) {                                                    \
            LOADSET(NXT, (((t) + 1) & 3) * BUF)   /* reads(t+1): 8 */          \
            asm volatile("s_waitcnt lgkmcnt(8)" ::: "memory"); /* t's done */  \
        } else {                                                               \
            asm volatile("s_waitcnt lgkmcnt(0)" ::: "memory");                 \
        }                                                                      \
        __builtin_amdgcn_sched_barrier(0);                                     \
        __builtin_amdgcn_s_setprio(1);                                         \
        MFMA16(CUR##a0, CUR##a1, CUR##a2, CUR##a3,                             \
               CUR##b0, CUR##b1, CUR##b2, CUR##b3)                             \
        __builtin_amdgcn_s_setprio(0);                                         \
        __builtin_amdgcn_s_barrier();                                          \
        __builtin_amdgcn_sched_barrier(0);                                     \
    }

    for (int t = 0; t < NT; t += 2) {
        CBODY(P, Q, t)
        CBODY(Q, P, t + 1)
    }
#undef CBODY
#undef LOADSET
#undef LDA
#undef LDB
#undef MFMA16

    // ---- epilogue: C/D layout col=lane&15, row=(lane>>4)*4+j ----
    const int crow0 = tm * BM + wm * 64 + ((lane >> 4) << 2);
    const int ccol0 = tn * BN + wn * 64 + frow;
    if constexpr (QUANT) {
        float c[16];
#pragma unroll
        for (int i = 0; i < 16; i++) c[i] = cb16[i];
        unsigned short* O = (unsigned short*)Cout;
#pragma unroll
        for (int m = 0; m < 4; m++)
#pragma unroll
            for (int n = 0; n < 4; n++)
#pragma unroll
                for (int j = 0; j < 4; j++)
                    O[(size_t)(crow0 + m * 16 + j) * 4096 + ccol0 + n * 16] =
                        f2h(quant16(acc[m][n][j] * 64.0f, c) * 0.015625f);
    } else {
        float* O = (float*)Cout;
#pragma unroll
        for (int m = 0; m < 4; m++)
#pragma unroll
            for (int n = 0; n < 4; n++)
#pragma unroll
                for (int j = 0; j < 4; j++)
                    O[(size_t)(crow0 + m * 16 + j) * 4096 + ccol0 + n * 16] =
                        acc[m][n][j];
    }
}

extern "C" void kernel_launch(void* const* d_in, const int* in_sizes, int n_in,
                              void* d_out, int out_size, void* d_ws,
                              size_t ws_size, hipStream_t stream) {
    const float* x = (const float*)d_in[0];
    const float* rot = (const float*)d_in[1];
    const float* cb = (const float*)d_in[2];
    float* out = (float*)d_out;

    unsigned short* Xh = (unsigned short*)d_ws;
    unsigned short* Rh = Xh + (size_t)2048 * 4096;
    unsigned short* Rt = Rh + (size_t)4096 * 4096;
    unsigned short* Yh = Rt + (size_t)4096 * 4096;

    (void)hipFuncSetAttribute(
        reinterpret_cast<const void*>(&gemm_nt_kernel<true>),
        hipFuncAttributeMaxDynamicSharedMemorySize, LDS_DYN);
    (void)hipFuncSetAttribute(
        reinterpret_cast<const void*>(&gemm_nt_kernel<false>),
        hipFuncAttributeMaxDynamicSharedMemorySize, LDS_DYN);

    convert_x_kernel<<<8192, 256, 0, stream>>>(x, Xh);
    conv_rot_kernel<<<dim3(64, 64), 256, 0, stream>>>(rot, Rh, Rt);
    // y = x @ R^T : NT GEMM, Bt = Rh
    gemm_nt_kernel<true><<<256, 768, LDS_DYN, stream>>>(Xh, Rh, (void*)Yh, cb);
    // x_hat = y_hat @ R = y_hat @ (R^T)^T : NT GEMM, Bt = Rt
    gemm_nt_kernel<false><<<256, 768, LDS_DYN, stream>>>(Yh, Rt, (void*)out, nullptr);
}